// Round 9
// baseline (284.551 us; speedup 1.0000x reference)
//
#include <hip/hip_runtime.h>
#include <math.h>

#define BB 4
#define HH 8
#define NN 2048
#define DD 64
#define KTOP 16
#define CUT_MARGIN 1e-3f

typedef _Float16 half_t;
typedef __attribute__((ext_vector_type(8))) _Float16 half8;
typedef __attribute__((ext_vector_type(4))) float floatx4;

// ---------------------------------------------------------------------------
// Kernel 1 (v8): L = (1/64) * sum_{h,d} q.k via f16x3 MFMA (16x16x32_f16).
// No split kernel. Per head: reg-stage fp32 tiles, convert ONCE per element
// (scalar RTN casts, bit-identical to the old split kernel), ds_write_b128
// into the v4-verified layout phys(r,u8) = (u8>>2)*4096 + (r>>3)*256 +
// (u8&3)*64 + (r&7)*8.
// CONFLICT-FREE WRITE MAPPING (v7 bug fixed): thread (w,a,c) handles unit
// p = ib*256 + w*64 + c*8 + a  ->  r = ib*32 + w*8 + c, u8 = a. Within an
// 8-lane phase group (a fixed, c = 0..7): byte%128 = c*16 -> 8 distinct
// slots, conflict-free (same algebra that matched v4's measured 0).
// T14: loads for head hh+1 issued between write-barrier and compute(hh),
// hiding HBM latency under the MFMA phase.
// Frag reads + MFMA order identical to v4 (absmax 0.0). 64KB LDS, 2 blk/CU.
// XCD-aware bijective remap (kept from v7: FETCH 74->59MB).
// ---------------------------------------------------------------------------
__global__ __launch_bounds__(256, 2) void gemm_conv(const float* __restrict__ q,
                                                    const float* __restrict__ kk,
                                                    float* __restrict__ L) {
    // XCD chunk remap (nwg=1024, divisible by 8 -> bijective)
    const int flat = blockIdx.x;
    const int swz  = (flat & 7) * 128 + (flat >> 3);
    const int j0 = (swz & 15) * 128;
    const int i0 = ((swz >> 4) & 15) * 128;
    const int b  = swz >> 8;

    const int tid  = threadIdx.x;
    const int wave = __builtin_amdgcn_readfirstlane(tid >> 6);
    const int lane = tid & 63;
    const int wr = wave >> 1, wc = wave & 1;
    const int lm = lane & 15, quad = lane >> 4;

    __shared__ __align__(16) half_t Ah[8192];   // 16KB each, 64KB total
    __shared__ __align__(16) half_t Al[8192];
    __shared__ __align__(16) half_t Bh[8192];
    __shared__ __align__(16) half_t Bl[8192];

    const float* gA = q  + ((size_t)(b * HH) * NN + i0) * DD;
    const float* gB = kk + ((size_t)(b * HH) * NN + j0) * DD;

    // stage decode: w = wave, a = lane>>3, c = lane&7
    const int sa = lane >> 3;
    const int sc = lane & 7;
    const int plocal  = wave * 64 + sc * 8 + sa;                 // [0,256)
    const int offbase = (sa >> 2) * 4096 + (sa & 3) * 64 + sc * 8 + wave * 256;
    // off(ib) = offbase + ib*1024   (max 8184 < 8192)

    floatx4 acc1[4][4], acc2[4][4];
#pragma unroll
    for (int tr = 0; tr < 4; ++tr)
#pragma unroll
        for (int tc = 0; tc < 4; ++tc) {
            acc1[tr][tc] = (floatx4)0.0f;
            acc2[tr][tc] = (floatx4)0.0f;
        }

    float4 v0[8], v1[8];

#define LOADREGS(hh_)                                                         \
    {                                                                         \
        const float* ga_ = gA + (size_t)(hh_) * (NN * DD);                    \
        const float* gb_ = gB + (size_t)(hh_) * (NN * DD);                    \
        _Pragma("unroll") for (int ib = 0; ib < 4; ++ib) {                    \
            const int p = ib * 256 + plocal;                                  \
            v0[ib]     = *(const float4*)(ga_ + (size_t)p * 8);               \
            v1[ib]     = *(const float4*)(ga_ + (size_t)p * 8 + 4);           \
            v0[4 + ib] = *(const float4*)(gb_ + (size_t)p * 8);               \
            v1[4 + ib] = *(const float4*)(gb_ + (size_t)p * 8 + 4);           \
        }                                                                     \
    }

    LOADREGS(0);

    for (int hh = 0; hh < HH; ++hh) {
        __syncthreads();   // previous MFMA phase done reading LDS

        // ---- convert once + conflict-free ds_write ----
#pragma unroll
        for (int ii = 0; ii < 8; ++ii) {
            const int ib = ii & 3;
            half_t* dh = (ii < 4) ? Ah : Bh;
            half_t* dl = (ii < 4) ? Al : Bl;
            const int off = offbase + ib * 1024;
            float aa[8] = {v0[ii].x, v0[ii].y, v0[ii].z, v0[ii].w,
                           v1[ii].x, v1[ii].y, v1[ii].z, v1[ii].w};
            half8 h, l;
#pragma unroll
            for (int e = 0; e < 8; ++e) {
                half_t hv = (half_t)aa[e];
                h[e] = hv;
                l[e] = (half_t)((aa[e] - (float)hv) * 2048.0f);
            }
            *(half8*)&dh[off] = h;
            *(half8*)&dl[off] = l;
        }

        __syncthreads();   // tile converted & visible

        if (hh < HH - 1) LOADREGS(hh + 1);   // T14: latency hides under MFMAs

        // ---- compute: 2 k-blocks of 32, v4-identical frag reads & MFMAs ----
#pragma unroll
        for (int ks = 0; ks < 2; ++ks) {
            half8 fah[4], fal[4], fbh[4], fbl[4];
#pragma unroll
            for (int t = 0; t < 4; ++t) {
                const int am = wr * 64 + t * 16 + lm;
                const int bm = wc * 64 + t * 16 + lm;
                const int ai = ks * 4096 + ((am >> 3) << 8) + (quad << 6) + ((am & 7) << 3);
                const int bi = ks * 4096 + ((bm >> 3) << 8) + (quad << 6) + ((bm & 7) << 3);
                fah[t] = *(const half8*)&Ah[ai];
                fal[t] = *(const half8*)&Al[ai];
                fbh[t] = *(const half8*)&Bh[bi];
                fbl[t] = *(const half8*)&Bl[bi];
            }
            __builtin_amdgcn_s_setprio(1);
#pragma unroll
            for (int tr = 0; tr < 4; ++tr)
#pragma unroll
                for (int tc = 0; tc < 4; ++tc) {
                    acc1[tr][tc] = __builtin_amdgcn_mfma_f32_16x16x32_f16(
                        fah[tr], fbh[tc], acc1[tr][tc], 0, 0, 0);
                    acc2[tr][tc] = __builtin_amdgcn_mfma_f32_16x16x32_f16(
                        fah[tr], fbl[tc], acc2[tr][tc], 0, 0, 0);
                    acc2[tr][tc] = __builtin_amdgcn_mfma_f32_16x16x32_f16(
                        fal[tr], fbh[tc], acc2[tr][tc], 0, 0, 0);
                }
            __builtin_amdgcn_s_setprio(0);
        }
    }
#undef LOADREGS

    const float s1 = 0.015625f;
    const float s2 = 0.015625f / 2048.0f;
#pragma unroll
    for (int tr = 0; tr < 4; ++tr)
#pragma unroll
        for (int r = 0; r < 4; ++r) {
            const int grow = i0 + wr * 64 + tr * 16 + quad * 4 + r;
            float* Lp = L + ((size_t)b * NN + grow) * NN + j0 + wc * 64 + lm;
#pragma unroll
            for (int tc = 0; tc < 4; ++tc)
                Lp[tc * 16] = acc1[tr][tc][r] * s1 + acc2[tr][tc][r] * s2;
        }
}

// ---------------------------------------------------------------------------
// Kernel 2: 4 independent rows per 256-thread block (one wave each) --
// wave-local algorithm, passed with absmax 0.0. Unchanged.
// ---------------------------------------------------------------------------
__device__ __forceinline__ unsigned long long flip64(double x) {
    unsigned long long v = (unsigned long long)__double_as_longlong(x);
    return v ^ ((0ULL - (v >> 63)) | 0x8000000000000000ULL);
}
__device__ __forceinline__ double unflip64(unsigned long long k) {
    unsigned long long v = (k >> 63) ? (k ^ 0x8000000000000000ULL) : ~k;
    return __longlong_as_double((long long)v);
}

__global__ __launch_bounds__(256) void topk_mask(float* __restrict__ LM,
                                                 const float* __restrict__ u) {
    const int wave = threadIdx.x >> 6;     // 0..3 (independent rows)
    const int lane = threadIdx.x & 63;     // 0..63, one wave
    const int row  = blockIdx.x * 4 + wave;
    float* lrow = LM + (size_t)row * NN;
    const float* urow = u + (size_t)row * NN;

    __shared__ int s_idx[4][64];

    // ---- phase A: stream row, keep only z + hard bitmask ----
    float z[32];
    unsigned hard = 0;
    float4 lb = *(const float4*)(lrow + lane * 4);
    float4 ub = *(const float4*)(urow + lane * 4);
#pragma unroll
    for (int e = 0; e < 8; ++e) {
        float4 lnx, unx;
        if (e < 7) {
            lnx = *(const float4*)(lrow + (e + 1) * 256 + lane * 4);
            unx = *(const float4*)(urow + (e + 1) * 256 + lane * 4);
        }
        const float* ls = (const float*)&lb;
        const float* us = (const float*)&ub;
#pragma unroll
        for (int s = 0; s < 4; ++s) {
            float w = -__logf(us[s] + 1e-9f);
            z[e * 4 + s] = ls[s] - __logf(w + 1e-9f);
            hard |= (us[s] > 0.999f ? 1u : 0u) << (e * 4 + s);
        }
        lb = lnx; ub = unx;
    }

    // ---- phase B: cutoff = (16th largest of 64 lane-maxima) - margin ----
    float v = z[0];
#pragma unroll
    for (int r = 1; r < 32; ++r) v = fmaxf(v, z[r]);
#pragma unroll
    for (int kS = 2; kS <= 64; kS <<= 1) {
#pragma unroll
        for (int j = kS >> 1; j > 0; j >>= 1) {
            float o = __shfl_xor(v, j, 64);
            bool asc = ((lane & kS) == 0);
            bool lower = ((lane & j) == 0);
            float mn = fminf(v, o), mx = fmaxf(v, o);
            v = (asc == lower) ? mn : mx;
        }
    }
    const float cut = __shfl(v, 48, 64) - CUT_MARGIN;

    // ---- phase C: ballot-prefix candidate gather (indices only) ----
    int c = 0;
#pragma unroll
    for (int r = 0; r < 32; ++r) {
        bool p = (z[r] >= cut);
        unsigned long long m = __ballot(p);
        if (p) {
            int slot = c + __popcll(m & ((1ULL << lane) - 1ULL));
            if (slot < 64) s_idx[wave][slot] = (r >> 2) * 256 + lane * 4 + (r & 3);
        }
        c += __popcll(m);
    }
    if (c > 64) c = 64;

    // ---- phase D: f64 keys; fixed 64-wide bitonic sort (ascending);
    //      threshold = sorted lane c-16 (exact 16th-largest z64) ----
    unsigned long long key = 0xFFFFFFFFFFFFFFFFULL;
    if (lane < c) {
        int idx = s_idx[wave][lane];
        double uu = (double)urow[idx] + 1e-9;   // cache-hot gather
        double w  = -log(uu);
        double g  = -log(w + 1e-9);
        key = flip64((double)lrow[idx] + g);
    }
#pragma unroll
    for (int kS = 2; kS <= 64; kS <<= 1) {
#pragma unroll
        for (int j = kS >> 1; j > 0; j >>= 1) {
            unsigned long long o = __shfl_xor(key, j, 64);
            bool asc = ((lane & kS) == 0);
            bool lower = ((lane & j) == 0);
            unsigned long long mn = (key < o) ? key : o;
            unsigned long long mx = (key < o) ? o : key;
            key = (asc == lower) ? mn : mx;
        }
    }
    const double thresh = unflip64(__shfl(key, c - KTOP, 64));

    // ---- phase E0: band|hard elements resolved in f64 ONCE, patch z ----
    const float t_hi = (float)thresh + 3e-4f;
    const float t_lo = (float)thresh - 3e-4f;
    unsigned bm = hard;
#pragma unroll
    for (int r = 0; r < 32; ++r)
        bm |= ((z[r] <= t_hi && z[r] >= t_lo) ? 1u : 0u) << r;
    while (bm) {           // expected ~0-2 iterations per wave, sparse exec
        int t = __builtin_ctz(bm);
        bm &= bm - 1;
        const int idx = (t >> 2) * 256 + lane * 4 + (t & 3);
        double uu = (double)urow[idx] + 1e-9;
        double w  = -log(uu);
        double g  = -log(w + 1e-9);
        double z64 = (double)lrow[idx] + g;    // L still intact (no stores yet)
        z[t] = (z64 >= thresh) ? 1.0e30f : -1.0e30f;
    }

    // ---- phase E1: pure-f32 store pass ----
#pragma unroll
    for (int e = 0; e < 8; ++e) {
        float o[4];
#pragma unroll
        for (int s = 0; s < 4; ++s)
            o[s] = (z[e * 4 + s] > t_hi) ? 1.0f : 0.0f;
        *(float4*)(lrow + e * 256 + lane * 4) = *(float4*)o;
    }
}

extern "C" void kernel_launch(void* const* d_in, const int* in_sizes, int n_in,
                              void* d_out, int out_size, void* d_ws, size_t ws_size,
                              hipStream_t stream) {
    const float* q = (const float*)d_in[0];
    const float* k = (const float*)d_in[1];
    const float* u = (const float*)d_in[2];
    float* out = (float*)d_out;          // logits scratch, then final mask
    (void)d_ws; (void)ws_size;           // no workspace needed

    gemm_conv<<<(NN / 128) * (NN / 128) * BB, 256, 0, stream>>>(q, k, out);

    topk_mask<<<BB * NN / 4, 256, 0, stream>>>(out, u);
}

// Round 10
// 231.700 us; speedup vs baseline: 1.2281x; 1.2281x over previous
//
#include <hip/hip_runtime.h>
#include <math.h>

#define BB 4
#define HH 8
#define NN 2048
#define DD 64
#define KTOP 16
#define CUT_MARGIN 1e-3f

typedef _Float16 half_t;
typedef __attribute__((ext_vector_type(8))) _Float16 half8;
typedef __attribute__((ext_vector_type(4))) float floatx4;

// ---------------------------------------------------------------------------
// Kernel 1 (v9): L = (1/64) * sum_{h,d} q.k via f16x3 MFMA (16x16x32_f16).
// No split kernel. Per head: reg-stage fp32 tiles, convert ONCE per element
// (scalar RTN casts), ds_write_b128 into the v4 layout phys(r,u8) =
// (u8>>2)*4096 + (r>>3)*256 + (u8&3)*64 + (r&7)*8.
// Write mapping (HW-VERIFIED conflict-free in R9: SQ_LDS_BANK_CONFLICT = 0):
// thread (w,a,c) handles unit p = ib*256 + w*64 + c*8 + a -> r = ib*32+w*8+c,
// u8 = a; 8-lane phase group (a fixed, c=0..7) hits 8 distinct 16B slots.
// v9 change vs v8: NO cross-phase load hoist (T14 caused 51MB of VGPR
// scratch spills). Loads issue at loop top BEFORE the barrier (regs only,
// no LDS hazard -> they fly during the barrier wait), die in the convert
// phase, never overlap frag registers. v7-measured spill-free pressure.
// Frag reads + MFMA order identical to v4 (absmax 0.0). 64KB LDS, 2 blk/CU.
// XCD-aware bijective remap (FETCH 74->59MB, kept).
// ---------------------------------------------------------------------------
__global__ __launch_bounds__(256, 2) void gemm_conv(const float* __restrict__ q,
                                                    const float* __restrict__ kk,
                                                    float* __restrict__ L) {
    // XCD chunk remap (nwg=1024, divisible by 8 -> bijective)
    const int flat = blockIdx.x;
    const int swz  = (flat & 7) * 128 + (flat >> 3);
    const int j0 = (swz & 15) * 128;
    const int i0 = ((swz >> 4) & 15) * 128;
    const int b  = swz >> 8;

    const int tid  = threadIdx.x;
    const int wave = __builtin_amdgcn_readfirstlane(tid >> 6);
    const int lane = tid & 63;
    const int wr = wave >> 1, wc = wave & 1;
    const int lm = lane & 15, quad = lane >> 4;

    __shared__ __align__(16) half_t Ah[8192];   // 16KB each, 64KB total
    __shared__ __align__(16) half_t Al[8192];
    __shared__ __align__(16) half_t Bh[8192];
    __shared__ __align__(16) half_t Bl[8192];

    const float* gA = q  + ((size_t)(b * HH) * NN + i0) * DD;
    const float* gB = kk + ((size_t)(b * HH) * NN + j0) * DD;

    // stage decode: w = wave, a = lane>>3, c = lane&7
    const int sa = lane >> 3;
    const int sc = lane & 7;
    const int plocal  = wave * 64 + sc * 8 + sa;                 // [0,256)
    const int offbase = (sa >> 2) * 4096 + (sa & 3) * 64 + sc * 8 + wave * 256;
    // off(ib) = offbase + ib*1024   (max 8184 < 8192)

    floatx4 acc1[4][4], acc2[4][4];
#pragma unroll
    for (int tr = 0; tr < 4; ++tr)
#pragma unroll
        for (int tc = 0; tc < 4; ++tc) {
            acc1[tr][tc] = (floatx4)0.0f;
            acc2[tr][tc] = (floatx4)0.0f;
        }

    for (int hh = 0; hh < HH; ++hh) {
        // ---- issue loads (regs only, no LDS hazard) before the barrier ----
        float4 v0[8], v1[8];
        {
            const float* ga_ = gA + (size_t)hh * (NN * DD);
            const float* gb_ = gB + (size_t)hh * (NN * DD);
#pragma unroll
            for (int ib = 0; ib < 4; ++ib) {
                const int p = ib * 256 + plocal;
                v0[ib]     = *(const float4*)(ga_ + (size_t)p * 8);
                v1[ib]     = *(const float4*)(ga_ + (size_t)p * 8 + 4);
                v0[4 + ib] = *(const float4*)(gb_ + (size_t)p * 8);
                v1[4 + ib] = *(const float4*)(gb_ + (size_t)p * 8 + 4);
            }
        }

        __syncthreads();   // previous MFMA phase done reading LDS

        // ---- convert once + conflict-free ds_write (verified 0 conflicts) ----
#pragma unroll
        for (int ii = 0; ii < 8; ++ii) {
            const int ib = ii & 3;
            half_t* dh = (ii < 4) ? Ah : Bh;
            half_t* dl = (ii < 4) ? Al : Bl;
            const int off = offbase + ib * 1024;
            float aa[8] = {v0[ii].x, v0[ii].y, v0[ii].z, v0[ii].w,
                           v1[ii].x, v1[ii].y, v1[ii].z, v1[ii].w};
            half8 h, l;
#pragma unroll
            for (int e = 0; e < 8; ++e) {
                half_t hv = (half_t)aa[e];
                h[e] = hv;
                l[e] = (half_t)((aa[e] - (float)hv) * 2048.0f);
            }
            *(half8*)&dh[off] = h;
            *(half8*)&dl[off] = l;
        }

        __syncthreads();   // tile converted & visible

        // ---- compute: 2 k-blocks of 32, v4-identical frag reads & MFMAs ----
#pragma unroll
        for (int ks = 0; ks < 2; ++ks) {
            half8 fah[4], fal[4], fbh[4], fbl[4];
#pragma unroll
            for (int t = 0; t < 4; ++t) {
                const int am = wr * 64 + t * 16 + lm;
                const int bm = wc * 64 + t * 16 + lm;
                const int ai = ks * 4096 + ((am >> 3) << 8) + (quad << 6) + ((am & 7) << 3);
                const int bi = ks * 4096 + ((bm >> 3) << 8) + (quad << 6) + ((bm & 7) << 3);
                fah[t] = *(const half8*)&Ah[ai];
                fal[t] = *(const half8*)&Al[ai];
                fbh[t] = *(const half8*)&Bh[bi];
                fbl[t] = *(const half8*)&Bl[bi];
            }
            __builtin_amdgcn_s_setprio(1);
#pragma unroll
            for (int tr = 0; tr < 4; ++tr)
#pragma unroll
                for (int tc = 0; tc < 4; ++tc) {
                    acc1[tr][tc] = __builtin_amdgcn_mfma_f32_16x16x32_f16(
                        fah[tr], fbh[tc], acc1[tr][tc], 0, 0, 0);
                    acc2[tr][tc] = __builtin_amdgcn_mfma_f32_16x16x32_f16(
                        fah[tr], fbl[tc], acc2[tr][tc], 0, 0, 0);
                    acc2[tr][tc] = __builtin_amdgcn_mfma_f32_16x16x32_f16(
                        fal[tr], fbh[tc], acc2[tr][tc], 0, 0, 0);
                }
            __builtin_amdgcn_s_setprio(0);
        }
    }

    const float s1 = 0.015625f;
    const float s2 = 0.015625f / 2048.0f;
#pragma unroll
    for (int tr = 0; tr < 4; ++tr)
#pragma unroll
        for (int r = 0; r < 4; ++r) {
            const int grow = i0 + wr * 64 + tr * 16 + quad * 4 + r;
            float* Lp = L + ((size_t)b * NN + grow) * NN + j0 + wc * 64 + lm;
#pragma unroll
            for (int tc = 0; tc < 4; ++tc)
                Lp[tc * 16] = acc1[tr][tc][r] * s1 + acc2[tr][tc][r] * s2;
        }
}

// ---------------------------------------------------------------------------
// Kernel 2: 4 independent rows per 256-thread block (one wave each) --
// wave-local algorithm, passed with absmax 0.0. Unchanged.
// ---------------------------------------------------------------------------
__device__ __forceinline__ unsigned long long flip64(double x) {
    unsigned long long v = (unsigned long long)__double_as_longlong(x);
    return v ^ ((0ULL - (v >> 63)) | 0x8000000000000000ULL);
}
__device__ __forceinline__ double unflip64(unsigned long long k) {
    unsigned long long v = (k >> 63) ? (k ^ 0x8000000000000000ULL) : ~k;
    return __longlong_as_double((long long)v);
}

__global__ __launch_bounds__(256) void topk_mask(float* __restrict__ LM,
                                                 const float* __restrict__ u) {
    const int wave = threadIdx.x >> 6;     // 0..3 (independent rows)
    const int lane = threadIdx.x & 63;     // 0..63, one wave
    const int row  = blockIdx.x * 4 + wave;
    float* lrow = LM + (size_t)row * NN;
    const float* urow = u + (size_t)row * NN;

    __shared__ int s_idx[4][64];

    // ---- phase A: stream row, keep only z + hard bitmask ----
    float z[32];
    unsigned hard = 0;
    float4 lb = *(const float4*)(lrow + lane * 4);
    float4 ub = *(const float4*)(urow + lane * 4);
#pragma unroll
    for (int e = 0; e < 8; ++e) {
        float4 lnx, unx;
        if (e < 7) {
            lnx = *(const float4*)(lrow + (e + 1) * 256 + lane * 4);
            unx = *(const float4*)(urow + (e + 1) * 256 + lane * 4);
        }
        const float* ls = (const float*)&lb;
        const float* us = (const float*)&ub;
#pragma unroll
        for (int s = 0; s < 4; ++s) {
            float w = -__logf(us[s] + 1e-9f);
            z[e * 4 + s] = ls[s] - __logf(w + 1e-9f);
            hard |= (us[s] > 0.999f ? 1u : 0u) << (e * 4 + s);
        }
        lb = lnx; ub = unx;
    }

    // ---- phase B: cutoff = (16th largest of 64 lane-maxima) - margin ----
    float v = z[0];
#pragma unroll
    for (int r = 1; r < 32; ++r) v = fmaxf(v, z[r]);
#pragma unroll
    for (int kS = 2; kS <= 64; kS <<= 1) {
#pragma unroll
        for (int j = kS >> 1; j > 0; j >>= 1) {
            float o = __shfl_xor(v, j, 64);
            bool asc = ((lane & kS) == 0);
            bool lower = ((lane & j) == 0);
            float mn = fminf(v, o), mx = fmaxf(v, o);
            v = (asc == lower) ? mn : mx;
        }
    }
    const float cut = __shfl(v, 48, 64) - CUT_MARGIN;

    // ---- phase C: ballot-prefix candidate gather (indices only) ----
    int c = 0;
#pragma unroll
    for (int r = 0; r < 32; ++r) {
        bool p = (z[r] >= cut);
        unsigned long long m = __ballot(p);
        if (p) {
            int slot = c + __popcll(m & ((1ULL << lane) - 1ULL));
            if (slot < 64) s_idx[wave][slot] = (r >> 2) * 256 + lane * 4 + (r & 3);
        }
        c += __popcll(m);
    }
    if (c > 64) c = 64;

    // ---- phase D: f64 keys; fixed 64-wide bitonic sort (ascending);
    //      threshold = sorted lane c-16 (exact 16th-largest z64) ----
    unsigned long long key = 0xFFFFFFFFFFFFFFFFULL;
    if (lane < c) {
        int idx = s_idx[wave][lane];
        double uu = (double)urow[idx] + 1e-9;   // cache-hot gather
        double w  = -log(uu);
        double g  = -log(w + 1e-9);
        key = flip64((double)lrow[idx] + g);
    }
#pragma unroll
    for (int kS = 2; kS <= 64; kS <<= 1) {
#pragma unroll
        for (int j = kS >> 1; j > 0; j >>= 1) {
            unsigned long long o = __shfl_xor(key, j, 64);
            bool asc = ((lane & kS) == 0);
            bool lower = ((lane & j) == 0);
            unsigned long long mn = (key < o) ? key : o;
            unsigned long long mx = (key < o) ? o : key;
            key = (asc == lower) ? mn : mx;
        }
    }
    const double thresh = unflip64(__shfl(key, c - KTOP, 64));

    // ---- phase E0: band|hard elements resolved in f64 ONCE, patch z ----
    const float t_hi = (float)thresh + 3e-4f;
    const float t_lo = (float)thresh - 3e-4f;
    unsigned bm = hard;
#pragma unroll
    for (int r = 0; r < 32; ++r)
        bm |= ((z[r] <= t_hi && z[r] >= t_lo) ? 1u : 0u) << r;
    while (bm) {           // expected ~0-2 iterations per wave, sparse exec
        int t = __builtin_ctz(bm);
        bm &= bm - 1;
        const int idx = (t >> 2) * 256 + lane * 4 + (t & 3);
        double uu = (double)urow[idx] + 1e-9;
        double w  = -log(uu);
        double g  = -log(w + 1e-9);
        double z64 = (double)lrow[idx] + g;    // L still intact (no stores yet)
        z[t] = (z64 >= thresh) ? 1.0e30f : -1.0e30f;
    }

    // ---- phase E1: pure-f32 store pass ----
#pragma unroll
    for (int e = 0; e < 8; ++e) {
        float o[4];
#pragma unroll
        for (int s = 0; s < 4; ++s)
            o[s] = (z[e * 4 + s] > t_hi) ? 1.0f : 0.0f;
        *(float4*)(lrow + e * 256 + lane * 4) = *(float4*)o;
    }
}

extern "C" void kernel_launch(void* const* d_in, const int* in_sizes, int n_in,
                              void* d_out, int out_size, void* d_ws, size_t ws_size,
                              hipStream_t stream) {
    const float* q = (const float*)d_in[0];
    const float* k = (const float*)d_in[1];
    const float* u = (const float*)d_in[2];
    float* out = (float*)d_out;          // logits scratch, then final mask
    (void)d_ws; (void)ws_size;           // no workspace needed

    gemm_conv<<<(NN / 128) * (NN / 128) * BB, 256, 0, stream>>>(q, k, out);

    topk_mask<<<BB * NN / 4, 256, 0, stream>>>(out, u);
}